// Round 2
// 750.026 us; speedup vs baseline: 1.0471x; 1.0471x over previous
//
#include <hip/hip_runtime.h>

// MyRNN: B=128, T=80, E=100, V=10000, U=512
// 8 clusters x 32 member-blocks, formed DYNAMICALLY by physical XCD
// (s_getreg HW_REG_XCC_ID + atomic slot grab): with 156KB LDS -> 1 block/CU,
// grid 256 fills all CUs, so each XCD hosts exactly 32 blocks -> a cluster's
// members share one L2 BY CONSTRUCTION (G16-sound, no mapping assumption).
// Cluster c owns batch rows [16c,16c+16); member m owns cols [16m,16m+16) of
// rk0/rk1/k1 (stationary in LDS, hi/lo bf16 split).
// R1: acquire/release -> buffer_inv/wbl2 thrash. Counter stays relaxed/MALL.
// R2-R6: ALL protocol variants pinned at 5.5-7us/exchange -> the invariant
//   was the DATA path: 8B uncached MALL transactions (~1M/exchange).
// R7: data path moved to XCD-local L2: plain stores (L1 write-through),
//   global_load_dwordx4 sc0 gathers (bypass L1, hit shared L2). Counter/post
//   protocol stayed on the MALL (single atomic counter, 32 serialized RMWs).
// R8: L2-resident plain-store flags + sc0 polls + barrier elision ->
//   container failed twice (signature of a spin-hang; plain-store flag
//   visibility via L1-wt->L2->sc0 is UNPROVEN, and two variables changed).
// R9: isolate the one win with R7-PROVEN primitives only. Keep R7's exact
//   barrier structure and data path. Replace the single MALL atomic counter
//   (32 serialized same-address RMWs + tid0 poll) with 32 per-member flag
//   words (32B stride) in the MALL:
//     post = vmcnt(0) drain, then lane0 __hip_atomic_store(relaxed, agent)
//            of the round id (same coherence point as R7's fetch_add, but
//            independent addresses -> posts land in PARALLEL, no RMW chain);
//     poll = wave-parallel __hip_atomic_load(relaxed, agent), lanes 0..31
//            each watch one member; __any(v < target) spin.
//   Flag value = round id (2t+1 after h0, 2t+2 after h1): monotonic, no
//   resets, deadlock-free by construction. End-of-kernel __threadfence
//   flushes dirty L2 exchange lines for graph-replay hygiene.

typedef __attribute__((ext_vector_type(8))) short short8;
typedef __attribute__((ext_vector_type(4))) float f32x4;

#define MFMA16(a,b,c) __builtin_amdgcn_mfma_f32_16x16x32_bf16(a,b,c,0,0,0)
#define LOAD_RLX(p)    __hip_atomic_load((p), __ATOMIC_RELAXED, __HIP_MEMORY_SCOPE_AGENT)
#define STORE_RLX(p,v) __hip_atomic_store((p), (v), __ATOMIC_RELAXED, __HIP_MEMORY_SCOPE_AGENT)
#define ADD_RLX(p,v)   __hip_atomic_fetch_add((p), (v), __ATOMIC_RELAXED, __HIP_MEMORY_SCOPE_AGENT)

__device__ __forceinline__ short f2bf(float v){
  unsigned u = __float_as_uint(v);
  u = (u + 0x7fffu + ((u >> 16) & 1u)) >> 16;   // RNE to bf16
  return (short)u;
}
__device__ __forceinline__ float bf2f(short s){
  return __uint_as_float(((unsigned)(unsigned short)s) << 16);
}
__device__ __forceinline__ float fast_tanh(float x){
  x = fminf(15.f, fmaxf(-15.f, x));
  float e = __expf(2.f * x);
  return (e - 1.f) * __builtin_amdgcn_rcpf(e + 1.f);
}

__launch_bounds__(128, 1)
__global__ void rnn_kernel(const int* __restrict__ tokens,
                           const float* __restrict__ emb,
                           const float* __restrict__ k0,
                           const float* __restrict__ rk0,
                           const float* __restrict__ b0,
                           const float* __restrict__ k1,
                           const float* __restrict__ rk1,
                           const float* __restrict__ b1,
                           const float* __restrict__ wd,
                           const float* __restrict__ bd,
                           float* __restrict__ out,
                           char* __restrict__ ws)
{
  constexpr int T = 80, E = 100, U = 512;
  const int tid  = threadIdx.x;
  const int w    = tid >> 6;          // wave id (0/1)
  const int lane = tid & 63;
  const int m    = lane & 15;         // row (A) / col (B,C)
  const int q    = lane >> 4;         // quad 0..3

  __shared__ __align__(16) short sW[6][16][520];   // rk0 hi/lo, rk1 hi/lo, k1 hi/lo : [col][k]
  __shared__ __align__(16) short sH[2][16][520];   // h / h0 staging hi,lo : [row][k]
  __shared__ __align__(16) short sE[2][16][136];   // emb rows hi,lo (K padded to 128 w/ zeros)
  __shared__ __align__(16) short sK0[2][16][136];  // k0 slice hi,lo : [col][k] (padded)
  __shared__ int   sTok[16][80];
  __shared__ float sB0[16], sB1[16];
  __shared__ float sRed[16][8];
  __shared__ int   sReg[2];

  int*      regCnt = (int*)(ws + 512);             // 8 registration counters, 64B stride (MALL)
  int*      flags  = (int*)(ws + 4096);            // [cl*32+mem] round-id flags, 32B stride (MALL)
  unsigned* hPk    = (unsigned*)(ws + 16*1024);    // h1 packed (hi<<16|lo), [128][512]
  unsigned* h0Pk   = hPk + 128*U;                  // h0 packed

  // -------- dynamic cluster formation: cluster id = physical XCD --------
  int xcc;
  asm volatile("s_getreg_b32 %0, hwreg(HW_REG_XCC_ID)" : "=s"(xcc));
  if (tid == 0){
    int slot = ADD_RLX(regCnt + (xcc & 7)*16, 1);  // 0..31 within this XCD
    sReg[0] = xcc & 7;
    sReg[1] = slot;
  }
  __syncthreads();
  const int cl  = sReg[0];
  const int mem = sReg[1];
  int* const myFlag   = flags + (cl*32 + mem)*8;          // this member's flag word (32B stride)
  int* const pollAddr = flags + (cl*32 + (lane & 31))*8;  // lane -> member flag map

  // ---------------- prologue: stationary weights -> LDS ----------------
  const float* mats[3] = { rk0, rk1, k1 };
  for (int mi = 0; mi < 3; ++mi){
    const float* G = mats[mi];
    for (int i = tid; i < 16*U; i += 128){
      int k = i >> 4, c = i & 15;
      float v  = G[k*U + mem*16 + c];
      short hi = f2bf(v);
      short lo = f2bf(v - bf2f(hi));
      sW[2*mi+0][c][k] = hi;
      sW[2*mi+1][c][k] = lo;
    }
  }
  for (int i = tid; i < 2*16*136; i += 128){ ((short*)sE)[i] = 0; ((short*)sK0)[i] = 0; }
  __syncthreads();
  for (int i = tid; i < 16*E; i += 128){
    int e = i >> 4, c = i & 15;
    float v  = k0[e*U + mem*16 + c];
    short hi = f2bf(v);
    short lo = f2bf(v - bf2f(hi));
    sK0[0][c][e] = hi; sK0[1][c][e] = lo;
  }
  for (int i = tid; i < 16*T; i += 128){
    int r = i / T, t = i - r*T;
    sTok[r][t] = tokens[(cl*16 + r)*T + t];
  }
  if (tid < 16){ sB0[tid] = b0[mem*16 + tid]; sB1[tid] = b1[mem*16 + tid]; }
  __syncthreads();

  // post: drain data stores to L2, then lane0 stores the round id to this
  // member's MALL flag word (agent-scope relaxed store — R7-proven path,
  // minus the RMW: independent addresses commit in parallel).
  auto post = [&](int val){
    asm volatile("s_waitcnt vmcnt(0)" ::: "memory");
    if (lane == 0) STORE_RLX(myFlag, val);
  };
  // wave-parallel poll: lanes 0..31 each watch one member's flag via the
  // R7-proven agent-scope relaxed load. One MALL round trip per iteration
  // checks all 32 members at once; no RMW serialization anywhere.
  auto pollFlags = [&](int target){
    while (__any(LOAD_RLX(pollAddr) < target)) {}
  };
  // L2 gather: 16x dwordx4 sc0 (bypass L1, hit XCD-shared L2), then unpack.
  auto gather = [&](const unsigned* srcPk){
    const uint4* s = (const uint4*)(srcPk + cl*16*U);   // 2048 uint4 = 32 KB
    uint4 r[16];
    #pragma unroll
    for (int j = 0; j < 16; ++j)
      asm volatile("global_load_dwordx4 %0, %1, off sc0"
                   : "=v"(r[j]) : "v"(&s[j*128 + tid]));
    asm volatile("s_waitcnt vmcnt(0)" ::: "memory");
    #pragma unroll
    for (int j = 0; j < 16; ++j){
      int i = j*128 + tid, row = i >> 7, c = (i & 127) * 4;
      unsigned h0 = (r[j].x >> 16)     | (r[j].y & 0xffff0000u);
      unsigned h1 = (r[j].z >> 16)     | (r[j].w & 0xffff0000u);
      unsigned l0 = (r[j].x & 0xffffu) | (r[j].y << 16);
      unsigned l1 = (r[j].z & 0xffffu) | (r[j].w << 16);
      uint2 hh; hh.x = h0; hh.y = h1;
      uint2 ll; ll.x = l0; ll.y = l1;
      *(uint2*)&sH[0][row][c] = hh;
      *(uint2*)&sH[1][row][c] = ll;
    }
  };

  const f32x4 zero4 = {0.f, 0.f, 0.f, 0.f};

  // ---------------- recurrence ----------------
  for (int t = 0; t < T; ++t){
    // stage emb rows into regs early (independent of exchange)
    float ev[13];
    #pragma unroll
    for (int p = 0; p < 13; ++p){
      int i = tid + p*128;
      ev[p] = (i < 16*E) ? emb[sTok[i/E][t]*E + (i % E)] : 0.f;
    }
    if (t > 0) pollFlags(2*t);             // all round-B(t-1) posts
    __syncthreads();
    if (t > 0) gather(hPk);
    #pragma unroll
    for (int p = 0; p < 13; ++p){
      int i = tid + p*128;
      if (i < 16*E){
        int row = i / E, e = i % E;
        short hi = f2bf(ev[p]);
        short lo = f2bf(ev[p] - bf2f(hi));
        sE[0][row][e] = hi; sE[1][row][e] = lo;
      }
    }
    __syncthreads();

    // ---- round A: wave0: h0 = tanh(x@k0 + h@rk0 + b0); wave1: h@rk1 partial
    f32x4 z1a = zero4, z1b = zero4, z1c = zero4, z1d = zero4;
    if (w == 0){
      f32x4 za = zero4, zb = zero4, zc = zero4, zd = zero4;
      #pragma unroll
      for (int kk = 0; kk < 4; ++kk){
        short8 ah = *(const short8*)&sE[0][m][kk*32 + q*8];
        short8 al = *(const short8*)&sE[1][m][kk*32 + q*8];
        short8 bh = *(const short8*)&sK0[0][m][kk*32 + q*8];
        short8 bl = *(const short8*)&sK0[1][m][kk*32 + q*8];
        za = MFMA16(ah, bh, za); zb = MFMA16(al, bh, zb);
        zc = MFMA16(ah, bl, zc); zd = MFMA16(al, bl, zd);
      }
      if (t > 0){
        #pragma unroll
        for (int kk = 0; kk < 16; ++kk){
          short8 ah = *(const short8*)&sH[0][m][kk*32 + q*8];
          short8 al = *(const short8*)&sH[1][m][kk*32 + q*8];
          short8 bh = *(const short8*)&sW[0][m][kk*32 + q*8];
          short8 bl = *(const short8*)&sW[1][m][kk*32 + q*8];
          za = MFMA16(ah, bh, za); zb = MFMA16(al, bh, zb);
          zc = MFMA16(ah, bl, zc); zd = MFMA16(al, bl, zd);
        }
      }
      f32x4 z = za; z += zb; z += zc; z += zd;
      #pragma unroll
      for (int r = 0; r < 4; ++r){
        float h0v = fast_tanh(z[r] + sB0[m]);
        short hi = f2bf(h0v);
        short lo = f2bf(h0v - bf2f(hi));
        int gr = cl*16 + q*4 + r, gc = mem*16 + m;
        unsigned pk = ((unsigned)(unsigned short)hi << 16) | (unsigned short)lo;
        h0Pk[gr*U + gc] = pk;              // plain store -> write-through to XCD L2
      }
      post(2*t + 1);                       // h0 ready (this member)
    } else {
      if (t > 0){
        #pragma unroll
        for (int kk = 0; kk < 16; ++kk){
          short8 ah = *(const short8*)&sH[0][m][kk*32 + q*8];
          short8 al = *(const short8*)&sH[1][m][kk*32 + q*8];
          short8 bh = *(const short8*)&sW[2][m][kk*32 + q*8];
          short8 bl = *(const short8*)&sW[3][m][kk*32 + q*8];
          z1a = MFMA16(ah, bh, z1a); z1b = MFMA16(al, bh, z1b);
          z1c = MFMA16(ah, bl, z1c); z1d = MFMA16(al, bl, z1d);
        }
      }
    }

    // ---- round B: h1 = tanh(h0@k1 + h@rk1 + b1)
    pollFlags(2*t + 1);                    // all round-A posts
    __syncthreads();                       // wave1's round-A sH reads must retire
    gather(h0Pk);
    __syncthreads();
    if (w == 1){
      f32x4 za = zero4, zb = zero4, zc = zero4, zd = zero4;
      #pragma unroll
      for (int kk = 0; kk < 16; ++kk){
        short8 ah = *(const short8*)&sH[0][m][kk*32 + q*8];
        short8 al = *(const short8*)&sH[1][m][kk*32 + q*8];
        short8 bh = *(const short8*)&sW[4][m][kk*32 + q*8];
        short8 bl = *(const short8*)&sW[5][m][kk*32 + q*8];
        za = MFMA16(ah, bh, za); zb = MFMA16(al, bh, zb);
        zc = MFMA16(ah, bl, zc); zd = MFMA16(al, bl, zd);
      }
      f32x4 z = za; z += zb; z += zc; z += zd;
      z += z1a; z += z1b; z += z1c; z += z1d;
      #pragma unroll
      for (int r = 0; r < 4; ++r){
        float h1v = fast_tanh(z[r] + sB1[m]);
        short hi = f2bf(h1v);
        short lo = f2bf(h1v - bf2f(hi));
        int gr = cl*16 + q*4 + r, gc = mem*16 + m;
        unsigned pk = ((unsigned)(unsigned short)hi << 16) | (unsigned short)lo;
        hPk[gr*U + gc] = pk;               // plain store -> XCD L2
      }
      post(2*t + 2);                       // h1 = h(t) ready (this member)
    }
    // no trailing barrier: loop-top poll+barrier aligns waves
  }

  // ---------------- epilogue: logits = h@wd + bd ; sigmoid ----------------
  if (mem == 0){
    pollFlags(2*T);
    __syncthreads();
    gather(hPk);
    __syncthreads();
    {
      int row = tid >> 3, seg = tid & 7;
      float acc = 0.f;
      for (int u = seg*64; u < seg*64 + 64; ++u){
        float hv = bf2f(sH[0][row][u]) + bf2f(sH[1][row][u]);
        acc += hv * wd[u];
      }
      sRed[row][seg] = acc;
    }
    __syncthreads();
    if (tid < 16){
      float s = bd[0];
      #pragma unroll
      for (int j = 0; j < 8; ++j) s += sRed[tid][j];
      out[cl*16 + tid] = 1.f / (1.f + __expf(-s));
    }
  }

  // replay hygiene: flush/invalidate this XCD's L2 exchange lines so no stale
  // dirty copies survive into the next graph replay (one-time cost)
  __threadfence();
}

extern "C" void kernel_launch(void* const* d_in, const int* in_sizes, int n_in,
                              void* d_out, int out_size, void* d_ws, size_t ws_size,
                              hipStream_t stream) {
  const int*   tokens = (const int*)  d_in[0];
  const float* emb    = (const float*)d_in[1];
  const float* k0     = (const float*)d_in[2];
  const float* rk0    = (const float*)d_in[3];
  const float* b0     = (const float*)d_in[4];
  const float* b1_    = (const float*)d_in[7];
  const float* k1     = (const float*)d_in[5];
  const float* rk1    = (const float*)d_in[6];
  const float* wd     = (const float*)d_in[8];
  const float* bd     = (const float*)d_in[9];

  // Zero registration counters + flag region (0xAA poison breaks monotonic
  // arith). Flags end at 4096 + 256*32 = 12288 < 16384; data starts at 16384.
  hipMemsetAsync(d_ws, 0, 16384, stream);

  hipLaunchKernelGGL(rnn_kernel, dim3(256), dim3(128), 0, stream,
                     tokens, emb, k0, rk0, b0, k1, rk1, b1_, wd, bd,
                     (float*)d_out, (char*)d_ws);
}